// Round 3
// baseline (947.550 us; speedup 1.0000x reference)
//
#include <hip/hip_runtime.h>
#include <hip/hip_bf16.h>
#include <math.h>

#define NN 50000
#define NE 800000
#define NEP 850000
#define NGRAPH 128
#define HEADS 8
#define CH 32
#define HID 256
#define NEG_SLOPE 0.2f

typedef __attribute__((ext_vector_type(8))) short short8;
typedef __attribute__((ext_vector_type(4))) short short4v;
typedef __attribute__((ext_vector_type(4))) float v4f;
typedef __attribute__((ext_vector_type(4))) unsigned uint4v;

__device__ inline float bflo(unsigned u) { return __builtin_bit_cast(float, u << 16); }
__device__ inline float bfhi(unsigned u) { return __builtin_bit_cast(float, u & 0xFFFF0000u); }
__device__ inline float bf2f(short s) {
    return __builtin_bit_cast(float, ((unsigned)(unsigned short)s) << 16);
}
__device__ inline short f2bf(float f) {
    __hip_bfloat16 b = __float2bfloat16(f);
    return __builtin_bit_cast(short, b);
}
// monotonic float<->uint order-preserving map (for atomicMax on floats)
__device__ inline unsigned fkey(float f) {
    unsigned u = __builtin_bit_cast(unsigned, f);
    return (u & 0x80000000u) ? ~u : (u | 0x80000000u);
}
__device__ inline float unfkey(unsigned u) {
    unsigned v = (u & 0x80000000u) ? (u & 0x7FFFFFFFu) : ~u;
    return __builtin_bit_cast(float, v);
}

// ---------------- fused prep ----------------
// blocks [0, 816): W swizzle-convert; per layer 272 cols: 0..255 = W cols,
//   cols 256..271 = wa[k][j] = sum_c W[k][head*32+c] * a[c]  (j<8: a_src head j; j>=8: a_dst head j-8)
// remaining blocks: edge count. counts[] pre-zeroed; self-loop = +1 in scans.

__global__ void prep_kernel(const float* __restrict__ W0, const float* __restrict__ Wh,
                            const float* __restrict__ as0, const float* __restrict__ ad0,
                            const float* __restrict__ ash, const float* __restrict__ adh,
                            short* __restrict__ Wt0, short* __restrict__ Wt1,
                            short* __restrict__ Wt2,
                            const int* __restrict__ dst, int* __restrict__ counts, int e) {
    int b = blockIdx.x;
    if (b < 816) {
        int which = b / 272;
        int n = b % 272;
        const float* W = (which == 0) ? W0 : (which == 1) ? Wh : Wh + 256 * 256;
        short* Wt = (which == 0) ? Wt0 : (which == 1) ? Wt1 : Wt2;
        const float* as = (which == 0) ? as0 : ash + (which - 1) * HEADS * CH;
        const float* ad = (which == 0) ? ad0 : adh + (which - 1) * HEADS * CH;
        int K = (which == 0) ? 128 : 256;
        int tile16 = n >> 4, l16 = n & 15;
        int KC = K >> 5;
        for (int k = threadIdx.x; k < K; k += blockDim.x) {
            float val;
            if (n < 256) {
                val = W[(size_t)k * 256 + n];
            } else {
                int j = n - 256;
                int head = j & 7;
                const float* a = (j < 8) ? (as + head * CH) : (ad + head * CH);
                float s = 0.f;
#pragma unroll
                for (int c = 0; c < CH; c++) s += W[(size_t)k * 256 + head * CH + c] * a[c];
                val = s;
            }
            int kc = k >> 5, quad = (k & 31) >> 3, j8 = k & 7;
            int lane = quad * 16 + l16;
            Wt[(size_t)(((tile16 * KC + kc) * 64 + lane)) * 8 + j8] = f2bf(val);
        }
    } else {
        int i = (b - 816) * 256 + threadIdx.x;
        if (i < e) atomicAdd(&counts[dst[i]], 1);
    }
}

__device__ inline int wave_incl_scan(int v, int lane) {
#pragma unroll
    for (int off = 1; off < 64; off <<= 1) {
        int u = __shfl_up(v, off);
        if (lane >= off) v += u;
    }
    return v;
}

__global__ __launch_bounds__(1024) void scan_part_kernel(const int* __restrict__ counts,
                                                         int* partial, int n) {
    int i = blockIdx.x * 1024 + threadIdx.x;
    int v = (i < n) ? counts[i] + 1 : 0;   // +1 self-loop
    int lane = threadIdx.x & 63, w = threadIdx.x >> 6;
    __shared__ int ws[16];
    int sv = wave_incl_scan(v, lane);
    if (lane == 63) ws[w] = sv;
    __syncthreads();
    if (threadIdx.x == 0) {
        int tot = 0;
#pragma unroll
        for (int j = 0; j < 16; j++) tot += ws[j];
        partial[blockIdx.x] = tot;
    }
}

// final scan; block-offset computed inline from partials (nb <= 64)
__global__ __launch_bounds__(1024) void scan_final_kernel(const int* __restrict__ counts,
                                                          const int* __restrict__ partial,
                                                          int* row_ptr, int* cursor, int n) {
    __shared__ int ws[17];
    __shared__ int s_off;
    int i = blockIdx.x * 1024 + threadIdx.x;
    int v = (i < n) ? counts[i] + 1 : 0;   // +1 self-loop
    int lane = threadIdx.x & 63, w = threadIdx.x >> 6;
    if (threadIdx.x < 64) {
        int pv = ((int)threadIdx.x < (int)blockIdx.x) ? partial[threadIdx.x] : 0;
#pragma unroll
        for (int off = 1; off < 64; off <<= 1) pv += __shfl_xor(pv, off);
        if (threadIdx.x == 0) s_off = pv;
    }
    int sv = wave_incl_scan(v, lane);
    if (lane == 63) ws[w] = sv;
    __syncthreads();
    if (w == 0) {
        int t = (lane < 16) ? ws[lane] : 0;
        int ts = wave_incl_scan(t, lane);
        if (lane < 16) ws[lane] = ts;
    }
    __syncthreads();
    int waveBase = (w > 0) ? ws[w - 1] : 0;
    int off = s_off;
    int incl = waveBase + sv;
    if (i < n) {
        int ex = off + incl - v;
        row_ptr[i] = ex;
        cursor[i] = ex;
        if (i == n - 1) row_ptr[n] = off + incl;
    }
}

__global__ void scatter_kernel(const int* __restrict__ ei, int* cursor, int* srcs,
                               int* dsts, int ne, int nn) {
    int i = blockIdx.x * blockDim.x + threadIdx.x;
    if (i < ne) {
        int s = ei[i];
        int d = ei[ne + i];
        int pos = atomicAdd(&cursor[d], 1);
        srcs[pos] = s;
        dsts[pos] = d;
    } else if (i < ne + nn) {
        int v = i - ne;
        int pos = atomicAdd(&cursor[v], 1);
        srcs[pos] = v;
        dsts[pos] = v;
    }
}

// ---------------- MFMA GEMM + algebraic alpha (17th B-tile) ----------------
// H[M,256](bf16) = A[M,K] @ W(swizzled, 17 tiles); tile 16 = wa -> alS/alD in f32 acc.
// block = 128 rows x 256 cols, 4 waves; wave = 64 rows x 128 cols (4x8 mfma tiles).
// H is written HEAD-MAJOR: [8][NN][32] so the attention gather working set per
// head (3.2 MB) fits one XCD's 4 MB L2. alS/alD head-major [8][NN].

#define EP_STRIDE 144

template <int K, bool AF32>
__global__ __launch_bounds__(256, 2) void gemm_mfma_kernel(const void* __restrict__ Ap,
                                                           const short* __restrict__ Wt,
                                                           short* __restrict__ H,
                                                           float* __restrict__ alS,
                                                           float* __restrict__ alD,
                                                           unsigned* __restrict__ gmaxU,
                                                           int M) {
    constexpr int KC = K >> 5;
    constexpr int ASTRIDE = K + 8;
    union LdsU {
        short a[128][ASTRIDE];
        short ep[4][64][EP_STRIDE];
    };
    __shared__ LdsU lds;
    __shared__ unsigned sm[HEADS];

    int t = threadIdx.x;
    int w = t >> 6;
    int lane = t & 63;
    int quad = lane >> 4, l16 = lane & 15;
    int wm = w & 1, wn = w >> 1;
    int m0 = blockIdx.x * 128;
    int m_base = m0 + wm * 64;
    int n_base = wn * 128;

    if (t < HEADS) sm[t] = 0u;

    // ---- stage A[128][K] into LDS, fully coalesced global reads ----
    if constexpr (AF32) {
        constexpr int C4 = K / 4;
        const float* A = (const float*)Ap;
        for (int s = t; s < 128 * C4; s += 256) {
            int row = s / C4;
            int c4 = s % C4;
            int gr = m0 + row; if (gr >= M) gr = M - 1;
            float4 v = *(const float4*)&A[(size_t)gr * K + c4 * 4];
            union { short4v s4; __hip_bfloat162 b[2]; } p;
            p.b[0] = __float22bfloat162_rn(make_float2(v.x, v.y));
            p.b[1] = __float22bfloat162_rn(make_float2(v.z, v.w));
            *(short4v*)&lds.a[row][c4 * 4] = p.s4;
        }
    } else {
        constexpr int C8 = K / 8;
        const short* A = (const short*)Ap;
        for (int s = t; s < 128 * C8; s += 256) {
            int row = s / C8;
            int c8 = s % C8;
            int gr = m0 + row; if (gr >= M) gr = M - 1;
            *(short8*)&lds.a[row][c8 * 8] = *(const short8*)&A[(size_t)gr * K + c8 * 8];
        }
    }
    __syncthreads();

    v4f acc[4][8] = {};
    v4f acce[4] = {};   // wa tile accumulators (wn==0 waves only; cols: l16<8 -> alS, else alD)
    const short* bw = Wt + ((size_t)(wn * 8) * KC * 64 + lane) * 8;
    const short* bwe = Wt + ((size_t)(16) * KC * 64 + lane) * 8;   // wa tile

#pragma unroll
    for (int kc = 0; kc < KC; kc++) {
        short8 b_frag[8];
#pragma unroll
        for (int nj = 0; nj < 8; nj++)
            b_frag[nj] = *(const short8*)(bw + (size_t)(nj * KC + kc) * 64 * 8);
        short8 a_frag[4];
#pragma unroll
        for (int mi = 0; mi < 4; mi++)
            a_frag[mi] = *(const short8*)&lds.a[wm * 64 + mi * 16 + l16][kc * 32 + quad * 8];
#pragma unroll
        for (int mi = 0; mi < 4; mi++)
#pragma unroll
            for (int nj = 0; nj < 8; nj++)
                acc[mi][nj] = __builtin_amdgcn_mfma_f32_16x16x32_bf16(a_frag[mi], b_frag[nj],
                                                                      acc[mi][nj], 0, 0, 0);
        if (wn == 0) {
            short8 be = *(const short8*)(bwe + (size_t)kc * 64 * 8);
#pragma unroll
            for (int mi = 0; mi < 4; mi++)
                acce[mi] = __builtin_amdgcn_mfma_f32_16x16x32_bf16(a_frag[mi], be,
                                                                   acce[mi], 0, 0, 0);
        }
    }
    __syncthreads();   // all lds.a reads complete before ep overwrite

    // ---- alS/alD write (head-major [8][NN]) + per-head max (wn==0 waves) ----
    if (wn == 0) {
        float hmax = -1e30f;   // head = l16 (only meaningful for l16 < 8)
#pragma unroll
        for (int mi = 0; mi < 4; mi++)
#pragma unroll
            for (int r = 0; r < 4; r++) {
                int row = m_base + mi * 16 + quad * 4 + r;
                float v = acce[mi][r];
                if (row < M) {
                    if (l16 < 8) {
                        alS[(size_t)l16 * NN + row] = v;
                        hmax = fmaxf(hmax, v);
                    } else {
                        alD[(size_t)(l16 - 8) * NN + row] = v;
                    }
                }
            }
        hmax = fmaxf(hmax, __shfl_xor(hmax, 16));
        hmax = fmaxf(hmax, __shfl_xor(hmax, 32));
        if (lane < 8) atomicMax(&sm[lane], fkey(hmax));
    }

#pragma unroll
    for (int mi = 0; mi < 4; mi++)
#pragma unroll
        for (int r = 0; r < 4; r++) {
            int rl = mi * 16 + quad * 4 + r;
#pragma unroll
            for (int nj = 0; nj < 8; nj++)
                lds.ep[w][rl][nj * 16 + l16] = f2bf(acc[mi][nj][r]);
        }
    __syncthreads();

    int rq = lane >> 4;
#pragma unroll
    for (int it = 0; it < 16; it++) {
        int rl = it * 4 + rq;
        int row = m_base + rl;
        if (row < M) {
            short8 v = *(const short8*)&lds.ep[w][rl][l16 * 8];
            int col = n_base + l16 * 8;
            int head = col >> 5;          // 0..7
            int off = col & 31;           // 0,8,16,24
            *(short8*)&H[((size_t)head * NN + row) * 32 + off] = v;
        }
    }
    if (t < HEADS) atomicMax(&gmaxU[t], sm[t]);
}

// ---------------- per-(edge,head) softmax weights (coalesced) ----------------
// w[h][i] = exp(leaky(alS[h][src]+alD[h][dst]) - m(h,dst)) ; same math as before,
// computed once per edge-head instead of 8x-redundantly inside the gather loop.

__global__ __launch_bounds__(256) void edgew_kernel(const int* __restrict__ srcs,
                                                    const int* __restrict__ dsts,
                                                    const float* __restrict__ alS,
                                                    const float* __restrict__ alD,
                                                    const unsigned* __restrict__ gmaxU,
                                                    float* __restrict__ wF, int ne) {
    int head = blockIdx.y;
    int i = blockIdx.x * 256 + threadIdx.x;
    if (i >= ne) return;
    int s = __builtin_nontemporal_load(&srcs[i]);
    int d = __builtin_nontemporal_load(&dsts[i]);
    float as = alS[(size_t)head * NN + s];
    float ad = alD[(size_t)head * NN + d];
    float gm = unfkey(gmaxU[head]) + ad;
    float m = fmaxf(gm, NEG_SLOPE * gm);
    float x = as + ad;
    x = fmaxf(x, NEG_SLOPE * x);
    float w = __expf(x - m);
    __builtin_nontemporal_store(w, &wF[(size_t)head * ne + i]);
}

// ---------------- head-split aggregation: one lane = one (node, head) ----------------
// head = blockIdx & 7 pins each head's 3.2 MB h-slice to one XCD L2 (round-robin
// dispatch). Lane serially walks its node's CSR segment (exactly deg iters, no
// clamping, no cross-lane reduce); owns all 32 channels (4x dwordx4 gathers, one
// address computation). Streaming data (srcs, wF, out) nontemporal so the h slice
// stays L2-resident.

#define ACC8(U, A0, A1) \
    A0.x += w * bflo(U.x); A0.y += w * bfhi(U.x); \
    A0.z += w * bflo(U.y); A0.w += w * bfhi(U.y); \
    A1.x += w * bflo(U.z); A1.y += w * bfhi(U.z); \
    A1.z += w * bflo(U.w); A1.w += w * bfhi(U.w);

__global__ __launch_bounds__(256, 4) void att_head_kernel(const short* __restrict__ h,
                                                          const float* __restrict__ wF,
                                                          const int* __restrict__ srcs,
                                                          const int* __restrict__ row_ptr,
                                                          const float* __restrict__ bias,
                                                          short* __restrict__ out, int n) {
    int head = blockIdx.x & 7;
    int node = (blockIdx.x >> 3) * 256 + threadIdx.x;
    if (node >= n) return;
    int lo = row_ptr[node], hi = row_ptr[node + 1];
    const short* hH = h + (size_t)head * NN * 32;
    const int* sp = srcs + lo;
    const float* wp = wF + (size_t)head * NEP + lo;

    float denom = 0.f;
    v4f A0 = {}, A1 = {}, A2 = {}, A3 = {}, A4 = {}, A5 = {}, A6 = {}, A7 = {};

#pragma unroll 2
    for (int e = lo; e < hi; ++e) {
        int s = __builtin_nontemporal_load(sp); sp++;
        float w = __builtin_nontemporal_load(wp); wp++;
        const uint4v* hv = (const uint4v*)(hH + (size_t)s * 32);
        uint4v q0 = hv[0];
        uint4v q1 = hv[1];
        uint4v q2 = hv[2];
        uint4v q3 = hv[3];
        denom += w;
        ACC8(q0, A0, A1)
        ACC8(q1, A2, A3)
        ACC8(q2, A4, A5)
        ACC8(q3, A6, A7)
    }

    float inv = 1.0f / (denom + 1e-16f);
    const float* bp = bias + head * 32;   // wave-uniform -> scalar loads
    union { uint4v u[4]; __hip_bfloat162 b[16]; } P;
#define PACK2(k, A) \
    P.b[2*(k)]   = __float22bfloat162_rn(make_float2(A.x * inv + bp[4*(k)],     A.y * inv + bp[4*(k)+1])); \
    P.b[2*(k)+1] = __float22bfloat162_rn(make_float2(A.z * inv + bp[4*(k)+2], A.w * inv + bp[4*(k)+3]));
    PACK2(0, A0) PACK2(1, A1) PACK2(2, A2) PACK2(3, A3)
    PACK2(4, A4) PACK2(5, A5) PACK2(6, A6) PACK2(7, A7)
#undef PACK2
    short* op = out + (size_t)node * HID + head * 32;
    __builtin_nontemporal_store(P.u[0], (uint4v*)op);
    __builtin_nontemporal_store(P.u[1], (uint4v*)(op + 8));
    __builtin_nontemporal_store(P.u[2], (uint4v*)(op + 16));
    __builtin_nontemporal_store(P.u[3], (uint4v*)(op + 24));
}

// ---------------- parallel mean pool (bf16 input) ----------------

#define POOL_CHUNK 64

__global__ __launch_bounds__(256) void pool_accum_kernel(const short* __restrict__ h,
                                                         const int* __restrict__ batch,
                                                         float* __restrict__ pooled,
                                                         int* __restrict__ cnt, int n) {
    int c0 = blockIdx.x * POOL_CHUNK;
    int c1 = c0 + POOL_CHUNK; if (c1 > n) c1 = n;
    int t = threadIdx.x;
    int g_cur = batch[c0];
    float acc = 0.f;
    int run = 0;
    for (int i = c0; i < c1; i++) {
        int g = batch[i];
        if (g != g_cur) {
            atomicAdd(&pooled[g_cur * HID + t], acc);
            if (t == 0) atomicAdd(&cnt[g_cur], run);
            acc = 0.f; run = 0; g_cur = g;
        }
        acc += bf2f(h[(size_t)i * HID + t]);
        run++;
    }
    atomicAdd(&pooled[g_cur * HID + t], acc);
    if (t == 0) atomicAdd(&cnt[g_cur], run);
}

// ---------------- final linear (with mean divide) ----------------

__global__ void final_kernel(const float* __restrict__ pooled, const int* __restrict__ cnt,
                             const float* __restrict__ W, const float* __restrict__ b,
                             float* __restrict__ out) {
    int idx = blockIdx.x * blockDim.x + threadIdx.x;
    if (idx >= NGRAPH * 10) return;
    int g = idx / 10, o = idx % 10;
    int c = cnt[g];
    float inv = 1.0f / (float)(c > 0 ? c : 1);
    float acc = b[o];
    for (int k = 0; k < HID; k++) acc += pooled[g * HID + k] * inv * W[k * 10 + o];
    out[idx] = acc;
}

extern "C" void kernel_launch(void* const* d_in, const int* in_sizes, int n_in,
                              void* d_out, int out_size, void* d_ws, size_t ws_size,
                              hipStream_t stream) {
    const float* x      = (const float*)d_in[0];
    const int*   ei     = (const int*)d_in[1];
    const int*   batch  = (const int*)d_in[2];
    const float* W0     = (const float*)d_in[3];
    const float* a_src0 = (const float*)d_in[4];
    const float* a_dst0 = (const float*)d_in[5];
    const float* b0     = (const float*)d_in[6];
    const float* Wh     = (const float*)d_in[7];   // [2,256,256]
    const float* a_srch = (const float*)d_in[8];   // [2,8,32]
    const float* a_dsth = (const float*)d_in[9];
    const float* bh     = (const float*)d_in[10];  // [2,256]
    const float* W_lin  = (const float*)d_in[11];
    const float* b_lin  = (const float*)d_in[12];
    float* out = (float*)d_out;

    // workspace carve-up (pooled..counts contiguous for single memset)
    short* hA     = (short*)d_ws;                    // 50000*256 bf16 (GEMM out, head-major [8][NN][32])
    short* hB     = hA + (size_t)NN * HID;           // 50000*256 bf16 (att out, node-major)
    short* Wt0    = hB + (size_t)NN * HID;           // 34816 (17-tile swizzled)
    short* Wt1    = Wt0 + 17 * 4 * 64 * 8;           // 69632
    short* Wt2    = Wt1 + 17 * 8 * 64 * 8;           // 69632
    float* alS    = (float*)(Wt2 + 17 * 8 * 64 * 8); // [8][NN]
    float* alD    = alS + (size_t)NN * HEADS;        // [8][NN]
    float* pooled = alD + (size_t)NN * HEADS;        // 128*256
    int* cnt      = (int*)(pooled + NGRAPH * HID);   // 128
    unsigned* gmaxA = (unsigned*)(cnt + NGRAPH);     // 24 (3 layers x 8 heads)
    int* counts   = (int*)(gmaxA + 24);              // 50000
    int* row_ptr  = counts + NN;                     // 50001
    int* cursor   = row_ptr + NN + 1;                // 50000
    int* srcs     = cursor + NN;                     // 850000
    int* dsts     = srcs + NEP;                      // 850000
    int* partial  = dsts + NEP;                      // 64
    float* wF     = (float*)(partial + 64);          // [8][NEP] = 27.2 MB

    const int NB_SCAN = (NN + 1023) / 1024;          // 49 <= 64
    const int NB_CNT = (NE + 255) / 256;             // 3125

    // single zero-init: pooled + cnt + gmaxA + counts
    hipMemsetAsync(pooled, 0, (NGRAPH * HID + NGRAPH + 24 + NN) * sizeof(float), stream);

    // fused W-swizzle (+wa cols) + edge-count
    prep_kernel<<<816 + NB_CNT, 256, 0, stream>>>(W0, Wh, a_src0, a_dst0, a_srch, a_dsth,
                                                  Wt0, Wt1, Wt2, ei + NE, counts, NE);
    scan_part_kernel<<<NB_SCAN, 1024, 0, stream>>>(counts, partial, NN);
    scan_final_kernel<<<NB_SCAN, 1024, 0, stream>>>(counts, partial, row_ptr, cursor, NN);
    scatter_kernel<<<(NEP + 255) / 256, 256, 0, stream>>>(ei, cursor, srcs, dsts, NE, NN);

    const int gemm_grid = (NN + 127) / 128;          // 391
    const int ew_gx = (NEP + 255) / 256;             // 3321
    const int agg_grid = ((NN + 255) / 256) * 8;     // 196 * 8

    for (int l = 0; l < 3; l++) {
        const float* bb = (l == 0) ? b0 : bh + (size_t)(l - 1) * HID;
        unsigned* gm = gmaxA + l * 8;

        if (l == 0)
            gemm_mfma_kernel<128, true><<<gemm_grid, 256, 0, stream>>>(
                x, Wt0, hA, alS, alD, gm, NN);
        else
            gemm_mfma_kernel<256, false><<<gemm_grid, 256, 0, stream>>>(
                hB, (l == 1) ? Wt1 : Wt2, hA, alS, alD, gm, NN);
        edgew_kernel<<<dim3(ew_gx, 8), 256, 0, stream>>>(srcs, dsts, alS, alD, gm, wF, NEP);
        att_head_kernel<<<agg_grid, 256, 0, stream>>>(hA, wF, srcs, row_ptr, bb, hB, NN);
    }

    // pool + final linear
    pool_accum_kernel<<<(NN + POOL_CHUNK - 1) / POOL_CHUNK, 256, 0, stream>>>(hB, batch, pooled, cnt, NN);
    final_kernel<<<(NGRAPH * 10 + 255) / 256, 256, 0, stream>>>(pooled, cnt, W_lin, b_lin, out);
}

// Round 6
// 833.432 us; speedup vs baseline: 1.1369x; 1.1369x over previous
//
#include <hip/hip_runtime.h>
#include <hip/hip_bf16.h>
#include <math.h>

#define NN 50000
#define NE 800000
#define NEP 850000
#define NGRAPH 128
#define HEADS 8
#define CH 32
#define HID 256
#define NEG_SLOPE 0.2f

typedef __attribute__((ext_vector_type(8))) short short8;
typedef __attribute__((ext_vector_type(4))) short short4v;
typedef __attribute__((ext_vector_type(4))) float v4f;
typedef __attribute__((ext_vector_type(2))) unsigned uint2v;

__device__ inline float bflo(unsigned u) { return __builtin_bit_cast(float, u << 16); }
__device__ inline float bfhi(unsigned u) { return __builtin_bit_cast(float, u & 0xFFFF0000u); }
__device__ inline float bf2f(short s) {
    return __builtin_bit_cast(float, ((unsigned)(unsigned short)s) << 16);
}
__device__ inline short f2bf(float f) {
    __hip_bfloat16 b = __float2bfloat16(f);
    return __builtin_bit_cast(short, b);
}
// monotonic float<->uint order-preserving map (for atomicMax on floats)
__device__ inline unsigned fkey(float f) {
    unsigned u = __builtin_bit_cast(unsigned, f);
    return (u & 0x80000000u) ? ~u : (u | 0x80000000u);
}
__device__ inline float unfkey(unsigned u) {
    unsigned v = (u & 0x80000000u) ? (u & 0x7FFFFFFFu) : ~u;
    return __builtin_bit_cast(float, v);
}

// ---------------- fused prep ----------------
// blocks [0, 816): W swizzle-convert; per layer 272 cols: 0..255 = W cols,
//   cols 256..271 = wa[k][j] = sum_c W[k][head*32+c] * a[c]  (j<8: a_src head j; j>=8: a_dst head j-8)
// remaining blocks: edge count. counts[] pre-zeroed; self-loop = +1 in scans.

__global__ void prep_kernel(const float* __restrict__ W0, const float* __restrict__ Wh,
                            const float* __restrict__ as0, const float* __restrict__ ad0,
                            const float* __restrict__ ash, const float* __restrict__ adh,
                            short* __restrict__ Wt0, short* __restrict__ Wt1,
                            short* __restrict__ Wt2,
                            const int* __restrict__ dst, int* __restrict__ counts, int e) {
    int b = blockIdx.x;
    if (b < 816) {
        int which = b / 272;
        int n = b % 272;
        const float* W = (which == 0) ? W0 : (which == 1) ? Wh : Wh + 256 * 256;
        short* Wt = (which == 0) ? Wt0 : (which == 1) ? Wt1 : Wt2;
        const float* as = (which == 0) ? as0 : ash + (which - 1) * HEADS * CH;
        const float* ad = (which == 0) ? ad0 : adh + (which - 1) * HEADS * CH;
        int K = (which == 0) ? 128 : 256;
        int tile16 = n >> 4, l16 = n & 15;
        int KC = K >> 5;
        for (int k = threadIdx.x; k < K; k += blockDim.x) {
            float val;
            if (n < 256) {
                val = W[(size_t)k * 256 + n];
            } else {
                int j = n - 256;
                int head = j & 7;
                const float* a = (j < 8) ? (as + head * CH) : (ad + head * CH);
                float s = 0.f;
#pragma unroll
                for (int c = 0; c < CH; c++) s += W[(size_t)k * 256 + head * CH + c] * a[c];
                val = s;
            }
            int kc = k >> 5, quad = (k & 31) >> 3, j8 = k & 7;
            int lane = quad * 16 + l16;
            Wt[(size_t)(((tile16 * KC + kc) * 64 + lane)) * 8 + j8] = f2bf(val);
        }
    } else {
        int i = (b - 816) * 256 + threadIdx.x;
        if (i < e) atomicAdd(&counts[dst[i]], 1);
    }
}

__device__ inline int wave_incl_scan(int v, int lane) {
#pragma unroll
    for (int off = 1; off < 64; off <<= 1) {
        int u = __shfl_up(v, off);
        if (lane >= off) v += u;
    }
    return v;
}

__global__ __launch_bounds__(1024) void scan_part_kernel(const int* __restrict__ counts,
                                                         int* partial, int n) {
    int i = blockIdx.x * 1024 + threadIdx.x;
    int v = (i < n) ? counts[i] + 1 : 0;   // +1 self-loop
    int lane = threadIdx.x & 63, w = threadIdx.x >> 6;
    __shared__ int ws[16];
    int sv = wave_incl_scan(v, lane);
    if (lane == 63) ws[w] = sv;
    __syncthreads();
    if (threadIdx.x == 0) {
        int tot = 0;
#pragma unroll
        for (int j = 0; j < 16; j++) tot += ws[j];
        partial[blockIdx.x] = tot;
    }
}

// final scan; block-offset computed inline from partials (nb <= 64)
__global__ __launch_bounds__(1024) void scan_final_kernel(const int* __restrict__ counts,
                                                          const int* __restrict__ partial,
                                                          int* row_ptr, int* cursor, int n) {
    __shared__ int ws[17];
    __shared__ int s_off;
    int i = blockIdx.x * 1024 + threadIdx.x;
    int v = (i < n) ? counts[i] + 1 : 0;   // +1 self-loop
    int lane = threadIdx.x & 63, w = threadIdx.x >> 6;
    if (threadIdx.x < 64) {
        int pv = ((int)threadIdx.x < (int)blockIdx.x) ? partial[threadIdx.x] : 0;
#pragma unroll
        for (int off = 1; off < 64; off <<= 1) pv += __shfl_xor(pv, off);
        if (threadIdx.x == 0) s_off = pv;
    }
    int sv = wave_incl_scan(v, lane);
    if (lane == 63) ws[w] = sv;
    __syncthreads();
    if (w == 0) {
        int t = (lane < 16) ? ws[lane] : 0;
        int ts = wave_incl_scan(t, lane);
        if (lane < 16) ws[lane] = ts;
    }
    __syncthreads();
    int waveBase = (w > 0) ? ws[w - 1] : 0;
    int off = s_off;
    int incl = waveBase + sv;
    if (i < n) {
        int ex = off + incl - v;
        row_ptr[i] = ex;
        cursor[i] = ex;
        if (i == n - 1) row_ptr[n] = off + incl;
    }
}

__global__ void scatter_kernel(const int* __restrict__ ei, int* cursor, int* srcs, int ne, int nn) {
    int i = blockIdx.x * blockDim.x + threadIdx.x;
    if (i < ne) {
        int s = ei[i];
        int d = ei[ne + i];
        int pos = atomicAdd(&cursor[d], 1);
        srcs[pos] = s;
    } else if (i < ne + nn) {
        int v = i - ne;
        int pos = atomicAdd(&cursor[v], 1);
        srcs[pos] = v;
    }
}

// ---------------- MFMA GEMM + algebraic alpha (17th B-tile) ----------------
// H[M,256](bf16) = A[M,K] @ W(swizzled, 17 tiles); tile 16 = wa -> alS/alD in f32 acc.
// block = 128 rows x 256 cols, 4 waves; wave = 64 rows x 128 cols (4x8 mfma tiles).
// H is written HEAD-MAJOR: [8][NN][32] so the attention gather working set per
// head (3.2 MB) fits one XCD's 4 MB L2. alS/alD head-major [8][NN].

#define EP_STRIDE 144

template <int K, bool AF32>
__global__ __launch_bounds__(256, 2) void gemm_mfma_kernel(const void* __restrict__ Ap,
                                                           const short* __restrict__ Wt,
                                                           short* __restrict__ H,
                                                           float* __restrict__ alS,
                                                           float* __restrict__ alD,
                                                           unsigned* __restrict__ gmaxU,
                                                           int M) {
    constexpr int KC = K >> 5;
    constexpr int ASTRIDE = K + 8;
    union LdsU {
        short a[128][ASTRIDE];
        short ep[4][64][EP_STRIDE];
    };
    __shared__ LdsU lds;
    __shared__ unsigned sm[HEADS];

    int t = threadIdx.x;
    int w = t >> 6;
    int lane = t & 63;
    int quad = lane >> 4, l16 = lane & 15;
    int wm = w & 1, wn = w >> 1;
    int m0 = blockIdx.x * 128;
    int m_base = m0 + wm * 64;
    int n_base = wn * 128;

    if (t < HEADS) sm[t] = 0u;

    // ---- stage A[128][K] into LDS, fully coalesced global reads ----
    if constexpr (AF32) {
        constexpr int C4 = K / 4;
        const float* A = (const float*)Ap;
        for (int s = t; s < 128 * C4; s += 256) {
            int row = s / C4;
            int c4 = s % C4;
            int gr = m0 + row; if (gr >= M) gr = M - 1;
            float4 v = *(const float4*)&A[(size_t)gr * K + c4 * 4];
            union { short4v s4; __hip_bfloat162 b[2]; } p;
            p.b[0] = __float22bfloat162_rn(make_float2(v.x, v.y));
            p.b[1] = __float22bfloat162_rn(make_float2(v.z, v.w));
            *(short4v*)&lds.a[row][c4 * 4] = p.s4;
        }
    } else {
        constexpr int C8 = K / 8;
        const short* A = (const short*)Ap;
        for (int s = t; s < 128 * C8; s += 256) {
            int row = s / C8;
            int c8 = s % C8;
            int gr = m0 + row; if (gr >= M) gr = M - 1;
            *(short8*)&lds.a[row][c8 * 8] = *(const short8*)&A[(size_t)gr * K + c8 * 8];
        }
    }
    __syncthreads();

    v4f acc[4][8] = {};
    v4f acce[4] = {};   // wa tile accumulators (wn==0 waves only; cols: l16<8 -> alS, else alD)
    const short* bw = Wt + ((size_t)(wn * 8) * KC * 64 + lane) * 8;
    const short* bwe = Wt + ((size_t)(16) * KC * 64 + lane) * 8;   // wa tile

#pragma unroll
    for (int kc = 0; kc < KC; kc++) {
        short8 b_frag[8];
#pragma unroll
        for (int nj = 0; nj < 8; nj++)
            b_frag[nj] = *(const short8*)(bw + (size_t)(nj * KC + kc) * 64 * 8);
        short8 a_frag[4];
#pragma unroll
        for (int mi = 0; mi < 4; mi++)
            a_frag[mi] = *(const short8*)&lds.a[wm * 64 + mi * 16 + l16][kc * 32 + quad * 8];
#pragma unroll
        for (int mi = 0; mi < 4; mi++)
#pragma unroll
            for (int nj = 0; nj < 8; nj++)
                acc[mi][nj] = __builtin_amdgcn_mfma_f32_16x16x32_bf16(a_frag[mi], b_frag[nj],
                                                                      acc[mi][nj], 0, 0, 0);
        if (wn == 0) {
            short8 be = *(const short8*)(bwe + (size_t)kc * 64 * 8);
#pragma unroll
            for (int mi = 0; mi < 4; mi++)
                acce[mi] = __builtin_amdgcn_mfma_f32_16x16x32_bf16(a_frag[mi], be,
                                                                   acce[mi], 0, 0, 0);
        }
    }
    __syncthreads();   // all lds.a reads complete before ep overwrite

    // ---- alS/alD write (head-major [8][NN]) + per-head max (wn==0 waves) ----
    if (wn == 0) {
        float hmax = -1e30f;   // head = l16 (only meaningful for l16 < 8)
#pragma unroll
        for (int mi = 0; mi < 4; mi++)
#pragma unroll
            for (int r = 0; r < 4; r++) {
                int row = m_base + mi * 16 + quad * 4 + r;
                float v = acce[mi][r];
                if (row < M) {
                    if (l16 < 8) {
                        alS[(size_t)l16 * NN + row] = v;
                        hmax = fmaxf(hmax, v);
                    } else {
                        alD[(size_t)(l16 - 8) * NN + row] = v;
                    }
                }
            }
        hmax = fmaxf(hmax, __shfl_xor(hmax, 16));
        hmax = fmaxf(hmax, __shfl_xor(hmax, 32));
        if (lane < 8) atomicMax(&sm[lane], fkey(hmax));
    }

#pragma unroll
    for (int mi = 0; mi < 4; mi++)
#pragma unroll
        for (int r = 0; r < 4; r++) {
            int rl = mi * 16 + quad * 4 + r;
#pragma unroll
            for (int nj = 0; nj < 8; nj++)
                lds.ep[w][rl][nj * 16 + l16] = f2bf(acc[mi][nj][r]);
        }
    __syncthreads();

    int rq = lane >> 4;
#pragma unroll
    for (int it = 0; it < 16; it++) {
        int rl = it * 4 + rq;
        int row = m_base + rl;
        if (row < M) {
            short8 v = *(const short8*)&lds.ep[w][rl][l16 * 8];
            int col = n_base + l16 * 8;
            int head = col >> 5;          // 0..7
            int off = col & 31;           // 0,8,16,24
            *(short8*)&H[((size_t)head * NN + row) * 32 + off] = v;
        }
    }
    if (t < HEADS) atomicMax(&gmaxU[t], sm[t]);
}

// ---------------- head-split fused attention, weight-once + bpermute ----------------
// head = blockIdx & 7 pins each head's 3.2 MB h-slice + 0.4 MB alS/alD to one XCD
// L2 (round-robin dispatch; confirmed by round-2's 35 MB FETCH). Wave = one
// (node, head). Per 64-edge chunk:
//   phase A: lane computes weight of edge (lo+lane): coalesced srcs load, aS
//            gather from resident table, ONE exp per edge-head; denom per-lane
//            (reduced over ALL 64 lanes at the end).
//   phase B: ceil(csize/8) groups; lane(sub,cl) bpermutes (s,w) of edge g*8+sub
//            from registers, gathers 8 B of the 64 B row (8-lane coalesced),
//            4 fmac; acc reduced over the sub bits only (each edge handled by
//            one sub-group, channels split across cl). Tail masked by w=0.

__global__ __launch_bounds__(256) void att_head_kernel(const short* __restrict__ h,   // [8][NN][32]
                                                       const float* __restrict__ alS, // [8][NN]
                                                       const float* __restrict__ alD, // [8][NN]
                                                       const unsigned* __restrict__ gmaxU,
                                                       const int* __restrict__ row_ptr,
                                                       const int* __restrict__ srcs,
                                                       const float* __restrict__ bias,
                                                       short* __restrict__ out, int n) {
    int head = blockIdx.x & 7;
    int node = (blockIdx.x >> 3) * 4 + (threadIdx.x >> 6);
    if (node >= n) return;
    int lane = threadIdx.x & 63;
    int sub = lane >> 3, cl = lane & 7;

    const short* hH = h + (size_t)head * NN * 32;
    const float* aS = alS + (size_t)head * NN;
    float ald = alD[(size_t)head * NN + node];
    float gm = unfkey(gmaxU[head]) + ald;
    float m = fmaxf(gm, NEG_SLOPE * gm);

    int lo = __builtin_nontemporal_load(&row_ptr[node]);
    int hi = __builtin_nontemporal_load(&row_ptr[node + 1]);

    float denom = 0.f;
    v4f acc = {};

    for (int base = lo; base < hi; base += 64) {
        int e = base + lane;
        int s = __builtin_nontemporal_load(&srcs[e < hi ? e : lo]);
        float x = aS[s] + ald;
        x = fmaxf(x, NEG_SLOPE * x);
        float w = (e < hi) ? __expf(x - m) : 0.f;
        denom += w;
        int csize = hi - base; if (csize > 64) csize = 64;
        int ng = (csize + 7) >> 3;
        int wb = __builtin_bit_cast(int, w);
        for (int g = 0; g < ng; ++g) {
            int idx = (g * 8 + sub) * 4;
            int sg = __builtin_amdgcn_ds_bpermute(idx, s);
            float wg = __builtin_bit_cast(float, __builtin_amdgcn_ds_bpermute(idx, wb));
            uint2 u = *(const uint2*)&hH[(size_t)sg * 32 + cl * 4];
            acc.x += wg * bflo(u.x);
            acc.y += wg * bfhi(u.x);
            acc.z += wg * bflo(u.y);
            acc.w += wg * bfhi(u.y);
        }
    }

    // denom: weights live one-per-lane (all 64 lanes) -> full 64-lane reduce
    denom += __shfl_xor(denom, 1);
    denom += __shfl_xor(denom, 2);
    denom += __shfl_xor(denom, 4);
    denom += __shfl_xor(denom, 8);
    denom += __shfl_xor(denom, 16);
    denom += __shfl_xor(denom, 32);
    // acc: each edge processed by exactly one sub-group -> reduce over sub bits
    acc.x += __shfl_xor(acc.x, 8);
    acc.x += __shfl_xor(acc.x, 16);
    acc.x += __shfl_xor(acc.x, 32);
    acc.y += __shfl_xor(acc.y, 8);
    acc.y += __shfl_xor(acc.y, 16);
    acc.y += __shfl_xor(acc.y, 32);
    acc.z += __shfl_xor(acc.z, 8);
    acc.z += __shfl_xor(acc.z, 16);
    acc.z += __shfl_xor(acc.z, 32);
    acc.w += __shfl_xor(acc.w, 8);
    acc.w += __shfl_xor(acc.w, 16);
    acc.w += __shfl_xor(acc.w, 32);

    if (sub == 0) {
        float inv = 1.0f / (denom + 1e-16f);
        float4 b4 = *(const float4*)&bias[head * 32 + cl * 4];
        union { uint2v u; __hip_bfloat162 b[2]; } p;
        p.b[0] = __float22bfloat162_rn(make_float2(acc.x * inv + b4.x, acc.y * inv + b4.y));
        p.b[1] = __float22bfloat162_rn(make_float2(acc.z * inv + b4.z, acc.w * inv + b4.w));
        __builtin_nontemporal_store(p.u, (uint2v*)&out[(size_t)node * HID + head * 32 + cl * 4]);
    }
}

// ---------------- parallel mean pool (bf16 input) ----------------

#define POOL_CHUNK 64

__global__ __launch_bounds__(256) void pool_accum_kernel(const short* __restrict__ h,
                                                         const int* __restrict__ batch,
                                                         float* __restrict__ pooled,
                                                         int* __restrict__ cnt, int n) {
    int c0 = blockIdx.x * POOL_CHUNK;
    int c1 = c0 + POOL_CHUNK; if (c1 > n) c1 = n;
    int t = threadIdx.x;
    int g_cur = batch[c0];
    float acc = 0.f;
    int run = 0;
    for (int i = c0; i < c1; i++) {
        int g = batch[i];
        if (g != g_cur) {
            atomicAdd(&pooled[g_cur * HID + t], acc);
            if (t == 0) atomicAdd(&cnt[g_cur], run);
            acc = 0.f; run = 0; g_cur = g;
        }
        acc += bf2f(h[(size_t)i * HID + t]);
        run++;
    }
    atomicAdd(&pooled[g_cur * HID + t], acc);
    if (t == 0) atomicAdd(&cnt[g_cur], run);
}

// ---------------- final linear (with mean divide) ----------------

__global__ void final_kernel(const float* __restrict__ pooled, const int* __restrict__ cnt,
                             const float* __restrict__ W, const float* __restrict__ b,
                             float* __restrict__ out) {
    int idx = blockIdx.x * blockDim.x + threadIdx.x;
    if (idx >= NGRAPH * 10) return;
    int g = idx / 10, o = idx % 10;
    int c = cnt[g];
    float inv = 1.0f / (float)(c > 0 ? c : 1);
    float acc = b[o];
    for (int k = 0; k < HID; k++) acc += pooled[g * HID + k] * inv * W[k * 10 + o];
    out[idx] = acc;
}

extern "C" void kernel_launch(void* const* d_in, const int* in_sizes, int n_in,
                              void* d_out, int out_size, void* d_ws, size_t ws_size,
                              hipStream_t stream) {
    const float* x      = (const float*)d_in[0];
    const int*   ei     = (const int*)d_in[1];
    const int*   batch  = (const int*)d_in[2];
    const float* W0     = (const float*)d_in[3];
    const float* a_src0 = (const float*)d_in[4];
    const float* a_dst0 = (const float*)d_in[5];
    const float* b0     = (const float*)d_in[6];
    const float* Wh     = (const float*)d_in[7];   // [2,256,256]
    const float* a_srch = (const float*)d_in[8];   // [2,8,32]
    const float* a_dsth = (const float*)d_in[9];
    const float* bh     = (const float*)d_in[10];  // [2,256]
    const float* W_lin  = (const float*)d_in[11];
    const float* b_lin  = (const float*)d_in[12];
    float* out = (float*)d_out;

    // workspace carve-up (pooled..counts contiguous for single memset)
    short* hA     = (short*)d_ws;                    // 50000*256 bf16 (GEMM out, head-major [8][NN][32])
    short* hB     = hA + (size_t)NN * HID;           // 50000*256 bf16 (att out, node-major)
    short* Wt0    = hB + (size_t)NN * HID;           // 34816 (17-tile swizzled)
    short* Wt1    = Wt0 + 17 * 4 * 64 * 8;           // 69632
    short* Wt2    = Wt1 + 17 * 8 * 64 * 8;           // 69632
    float* alS    = (float*)(Wt2 + 17 * 8 * 64 * 8); // [8][NN]
    float* alD    = alS + (size_t)NN * HEADS;        // [8][NN]
    float* pooled = alD + (size_t)NN * HEADS;        // 128*256
    int* cnt      = (int*)(pooled + NGRAPH * HID);   // 128
    unsigned* gmaxA = (unsigned*)(cnt + NGRAPH);     // 24 (3 layers x 8 heads)
    int* counts   = (int*)(gmaxA + 24);              // 50000
    int* row_ptr  = counts + NN;                     // 50001
    int* cursor   = row_ptr + NN + 1;                // 50000
    int* srcs     = cursor + NN;                     // 850000
    int* partial  = srcs + NEP;                      // 64

    const int NB_SCAN = (NN + 1023) / 1024;          // 49 <= 64
    const int NB_CNT = (NE + 255) / 256;             // 3125

    // single zero-init: pooled + cnt + gmaxA + counts
    hipMemsetAsync(pooled, 0, (NGRAPH * HID + NGRAPH + 24 + NN) * sizeof(float), stream);

    // fused W-swizzle (+wa cols) + edge-count
    prep_kernel<<<816 + NB_CNT, 256, 0, stream>>>(W0, Wh, a_src0, a_dst0, a_srch, a_dsth,
                                                  Wt0, Wt1, Wt2, ei + NE, counts, NE);
    scan_part_kernel<<<NB_SCAN, 1024, 0, stream>>>(counts, partial, NN);
    scan_final_kernel<<<NB_SCAN, 1024, 0, stream>>>(counts, partial, row_ptr, cursor, NN);
    scatter_kernel<<<(NEP + 255) / 256, 256, 0, stream>>>(ei, cursor, srcs, NE, NN);

    const int gemm_grid = (NN + 127) / 128;          // 391
    const int agg_grid = ((NN + 3) / 4) * 8;         // 12500 node-groups x 8 heads

    for (int l = 0; l < 3; l++) {
        const float* bb = (l == 0) ? b0 : bh + (size_t)(l - 1) * HID;
        unsigned* gm = gmaxA + l * 8;

        if (l == 0)
            gemm_mfma_kernel<128, true><<<gemm_grid, 256, 0, stream>>>(
                x, Wt0, hA, alS, alD, gm, NN);
        else
            gemm_mfma_kernel<256, false><<<gemm_grid, 256, 0, stream>>>(
                hB, (l == 1) ? Wt1 : Wt2, hA, alS, alD, gm, NN);
        att_head_kernel<<<agg_grid, 256, 0, stream>>>(hA, alS, alD, gm, row_ptr, srcs, bb, hB, NN);
    }

    // pool + final linear
    pool_accum_kernel<<<(NN + POOL_CHUNK - 1) / POOL_CHUNK, 256, 0, stream>>>(hB, batch, pooled, cnt, NN);
    final_kernel<<<(NGRAPH * 10 + 255) / 256, 256, 0, stream>>>(pooled, cnt, W_lin, b_lin, out);
}

// Round 7
// 509.863 us; speedup vs baseline: 1.8584x; 1.6346x over previous
//
#include <hip/hip_runtime.h>
#include <hip/hip_bf16.h>
#include <math.h>

#define NN 50000
#define NE 800000
#define NGRAPH 128
#define HEADS 8
#define CH 32
#define HID 256
#define NEG_SLOPE 0.2f

typedef __attribute__((ext_vector_type(8))) short short8;
typedef __attribute__((ext_vector_type(4))) short short4v;
typedef __attribute__((ext_vector_type(4))) float v4f;
typedef __attribute__((ext_vector_type(2))) unsigned uint2v;

__device__ inline float bflo(unsigned u) { return __builtin_bit_cast(float, u << 16); }
__device__ inline float bfhi(unsigned u) { return __builtin_bit_cast(float, u & 0xFFFF0000u); }
__device__ inline float bf2f(short s) {
    return __builtin_bit_cast(float, ((unsigned)(unsigned short)s) << 16);
}
__device__ inline short f2bf(float f) {
    __hip_bfloat16 b = __float2bfloat16(f);
    return __builtin_bit_cast(short, b);
}
// monotonic float<->uint order-preserving map (for atomicMax on floats)
__device__ inline unsigned fkey(float f) {
    unsigned u = __builtin_bit_cast(unsigned, f);
    return (u & 0x80000000u) ? ~u : (u | 0x80000000u);
}
__device__ inline float unfkey(unsigned u) {
    unsigned v = (u & 0x80000000u) ? (u & 0x7FFFFFFFu) : ~u;
    return __builtin_bit_cast(float, v);
}

// ---------------- fused prep ----------------
// blocks [0, 816): W swizzle-convert; per layer 272 cols: 0..255 = W cols,
//   cols 256..271 = wa[k][j] = sum_c W[k][head*32+c] * a[c]  (j<8: a_src head j; j>=8: a_dst head j-8)
// remaining blocks: edge count. counts[] pre-zeroed; self-loop = +1 in scans.

__global__ void prep_kernel(const float* __restrict__ W0, const float* __restrict__ Wh,
                            const float* __restrict__ as0, const float* __restrict__ ad0,
                            const float* __restrict__ ash, const float* __restrict__ adh,
                            short* __restrict__ Wt0, short* __restrict__ Wt1,
                            short* __restrict__ Wt2,
                            const int* __restrict__ dst, int* __restrict__ counts, int e) {
    int b = blockIdx.x;
    if (b < 816) {
        int which = b / 272;
        int n = b % 272;
        const float* W = (which == 0) ? W0 : (which == 1) ? Wh : Wh + 256 * 256;
        short* Wt = (which == 0) ? Wt0 : (which == 1) ? Wt1 : Wt2;
        const float* as = (which == 0) ? as0 : ash + (which - 1) * HEADS * CH;
        const float* ad = (which == 0) ? ad0 : adh + (which - 1) * HEADS * CH;
        int K = (which == 0) ? 128 : 256;
        int tile16 = n >> 4, l16 = n & 15;
        int KC = K >> 5;
        for (int k = threadIdx.x; k < K; k += blockDim.x) {
            float val;
            if (n < 256) {
                val = W[(size_t)k * 256 + n];
            } else {
                int j = n - 256;
                int head = j & 7;
                const float* a = (j < 8) ? (as + head * CH) : (ad + head * CH);
                float s = 0.f;
#pragma unroll
                for (int c = 0; c < CH; c++) s += W[(size_t)k * 256 + head * CH + c] * a[c];
                val = s;
            }
            int kc = k >> 5, quad = (k & 31) >> 3, j8 = k & 7;
            int lane = quad * 16 + l16;
            Wt[(size_t)(((tile16 * KC + kc) * 64 + lane)) * 8 + j8] = f2bf(val);
        }
    } else {
        int i = (b - 816) * 256 + threadIdx.x;
        if (i < e) atomicAdd(&counts[dst[i]], 1);
    }
}

__device__ inline int wave_incl_scan(int v, int lane) {
#pragma unroll
    for (int off = 1; off < 64; off <<= 1) {
        int u = __shfl_up(v, off);
        if (lane >= off) v += u;
    }
    return v;
}

__global__ __launch_bounds__(1024) void scan_part_kernel(const int* __restrict__ counts,
                                                         int* partial, int n) {
    int i = blockIdx.x * 1024 + threadIdx.x;
    int v = (i < n) ? counts[i] + 1 : 0;   // +1 self-loop
    int lane = threadIdx.x & 63, w = threadIdx.x >> 6;
    __shared__ int ws[16];
    int sv = wave_incl_scan(v, lane);
    if (lane == 63) ws[w] = sv;
    __syncthreads();
    if (threadIdx.x == 0) {
        int tot = 0;
#pragma unroll
        for (int j = 0; j < 16; j++) tot += ws[j];
        partial[blockIdx.x] = tot;
    }
}

// final scan; block-offset computed inline from partials (nb <= 64)
__global__ __launch_bounds__(1024) void scan_final_kernel(const int* __restrict__ counts,
                                                          const int* __restrict__ partial,
                                                          int* row_ptr, int* cursor, int n) {
    __shared__ int ws[17];
    __shared__ int s_off;
    int i = blockIdx.x * 1024 + threadIdx.x;
    int v = (i < n) ? counts[i] + 1 : 0;   // +1 self-loop
    int lane = threadIdx.x & 63, w = threadIdx.x >> 6;
    if (threadIdx.x < 64) {
        int pv = ((int)threadIdx.x < (int)blockIdx.x) ? partial[threadIdx.x] : 0;
#pragma unroll
        for (int off = 1; off < 64; off <<= 1) pv += __shfl_xor(pv, off);
        if (threadIdx.x == 0) s_off = pv;
    }
    int sv = wave_incl_scan(v, lane);
    if (lane == 63) ws[w] = sv;
    __syncthreads();
    if (w == 0) {
        int t = (lane < 16) ? ws[lane] : 0;
        int ts = wave_incl_scan(t, lane);
        if (lane < 16) ws[lane] = ts;
    }
    __syncthreads();
    int waveBase = (w > 0) ? ws[w - 1] : 0;
    int off = s_off;
    int incl = waveBase + sv;
    if (i < n) {
        int ex = off + incl - v;
        row_ptr[i] = ex;
        cursor[i] = ex;
        if (i == n - 1) row_ptr[n] = off + incl;
    }
}

__global__ void scatter_kernel(const int* __restrict__ ei, int* cursor, int* srcs, int ne, int nn) {
    int i = blockIdx.x * blockDim.x + threadIdx.x;
    if (i < ne) {
        int s = ei[i];
        int d = ei[ne + i];
        int pos = atomicAdd(&cursor[d], 1);
        srcs[pos] = s;
    } else if (i < ne + nn) {
        int v = i - ne;
        int pos = atomicAdd(&cursor[v], 1);
        srcs[pos] = v;
    }
}

// ---------------- MFMA GEMM + algebraic alpha (17th B-tile) ----------------
// H[M,256](bf16) = A[M,K] @ W(swizzled, 17 tiles); tile 16 = wa -> alS/alD in f32 acc.
// block = 128 rows x 256 cols, 4 waves; wave = 64 rows x 128 cols (4x8 mfma tiles).
// Waves with wn==0 additionally compute the wa tile for their 64 rows (+4 MFMA/kc).

#define EP_STRIDE 144

template <int K, bool AF32>
__global__ __launch_bounds__(256, 2) void gemm_mfma_kernel(const void* __restrict__ Ap,
                                                           const short* __restrict__ Wt,
                                                           short* __restrict__ H,
                                                           float* __restrict__ alS,
                                                           float* __restrict__ alD,
                                                           unsigned* __restrict__ gmaxU,
                                                           int M) {
    constexpr int KC = K >> 5;
    constexpr int ASTRIDE = K + 8;
    union LdsU {
        short a[128][ASTRIDE];
        short ep[4][64][EP_STRIDE];
    };
    __shared__ LdsU lds;
    __shared__ unsigned sm[HEADS];

    int t = threadIdx.x;
    int w = t >> 6;
    int lane = t & 63;
    int quad = lane >> 4, l16 = lane & 15;
    int wm = w & 1, wn = w >> 1;
    int m0 = blockIdx.x * 128;
    int m_base = m0 + wm * 64;
    int n_base = wn * 128;

    if (t < HEADS) sm[t] = 0u;

    // ---- stage A[128][K] into LDS, fully coalesced global reads ----
    if constexpr (AF32) {
        constexpr int C4 = K / 4;
        const float* A = (const float*)Ap;
        for (int s = t; s < 128 * C4; s += 256) {
            int row = s / C4;
            int c4 = s % C4;
            int gr = m0 + row; if (gr >= M) gr = M - 1;
            float4 v = *(const float4*)&A[(size_t)gr * K + c4 * 4];
            union { short4v s4; __hip_bfloat162 b[2]; } p;
            p.b[0] = __float22bfloat162_rn(make_float2(v.x, v.y));
            p.b[1] = __float22bfloat162_rn(make_float2(v.z, v.w));
            *(short4v*)&lds.a[row][c4 * 4] = p.s4;
        }
    } else {
        constexpr int C8 = K / 8;
        const short* A = (const short*)Ap;
        for (int s = t; s < 128 * C8; s += 256) {
            int row = s / C8;
            int c8 = s % C8;
            int gr = m0 + row; if (gr >= M) gr = M - 1;
            *(short8*)&lds.a[row][c8 * 8] = *(const short8*)&A[(size_t)gr * K + c8 * 8];
        }
    }
    __syncthreads();

    v4f acc[4][8] = {};
    v4f acce[4] = {};   // wa tile accumulators (wn==0 waves only; cols: l16<8 -> alS, else alD)
    // swizzled B base for this wave: tiles wn*8 .. wn*8+7
    const short* bw = Wt + ((size_t)(wn * 8) * KC * 64 + lane) * 8;
    const short* bwe = Wt + ((size_t)(16) * KC * 64 + lane) * 8;   // wa tile

#pragma unroll
    for (int kc = 0; kc < KC; kc++) {
        short8 b_frag[8];
#pragma unroll
        for (int nj = 0; nj < 8; nj++)
            b_frag[nj] = *(const short8*)(bw + (size_t)(nj * KC + kc) * 64 * 8);
        short8 a_frag[4];
#pragma unroll
        for (int mi = 0; mi < 4; mi++)
            a_frag[mi] = *(const short8*)&lds.a[wm * 64 + mi * 16 + l16][kc * 32 + quad * 8];
#pragma unroll
        for (int mi = 0; mi < 4; mi++)
#pragma unroll
            for (int nj = 0; nj < 8; nj++)
                acc[mi][nj] = __builtin_amdgcn_mfma_f32_16x16x32_bf16(a_frag[mi], b_frag[nj],
                                                                      acc[mi][nj], 0, 0, 0);
        if (wn == 0) {
            short8 be = *(const short8*)(bwe + (size_t)kc * 64 * 8);
#pragma unroll
            for (int mi = 0; mi < 4; mi++)
                acce[mi] = __builtin_amdgcn_mfma_f32_16x16x32_bf16(a_frag[mi], be,
                                                                   acce[mi], 0, 0, 0);
        }
    }
    __syncthreads();   // all lds.a reads complete before ep overwrite

    // ---- alS/alD write + per-head max (wn==0 waves; rows m_base..m_base+63) ----
    if (wn == 0) {
        float hmax = -1e30f;   // head = l16 (only meaningful for l16 < 8)
#pragma unroll
        for (int mi = 0; mi < 4; mi++)
#pragma unroll
            for (int r = 0; r < 4; r++) {
                int row = m_base + mi * 16 + quad * 4 + r;
                float v = acce[mi][r];
                if (row < M) {
                    if (l16 < 8) {
                        alS[row * HEADS + l16] = v;
                        hmax = fmaxf(hmax, v);
                    } else {
                        alD[row * HEADS + (l16 - 8)] = v;
                    }
                }
            }
        hmax = fmaxf(hmax, __shfl_xor(hmax, 16));
        hmax = fmaxf(hmax, __shfl_xor(hmax, 32));
        if (lane < 8) atomicMax(&sm[lane], fkey(hmax));
    }

#pragma unroll
    for (int mi = 0; mi < 4; mi++)
#pragma unroll
        for (int r = 0; r < 4; r++) {
            int rl = mi * 16 + quad * 4 + r;
#pragma unroll
            for (int nj = 0; nj < 8; nj++)
                lds.ep[w][rl][nj * 16 + l16] = f2bf(acc[mi][nj][r]);
        }
    __syncthreads();

    int rq = lane >> 4;
#pragma unroll
    for (int it = 0; it < 16; it++) {
        int rl = it * 4 + rq;
        int row = m_base + rl;
        if (row < M) {
            short8 v = *(const short8*)&lds.ep[w][rl][l16 * 8];
            *(short8*)&H[(size_t)row * HID + n_base + l16 * 8] = v;
        }
    }
    if (t < HEADS) atomicMax(&gmaxU[t], sm[t]);
}

// ---------------- fused attention: fixed-shift softmax, lane-parallel weights ----------------
// one wave per node; lane = head*8+sub owns channels [lane*4, lane*4+4)
// srcs loads + out stores nontemporal: keep the streaming data out of L2 so the
// 25.6 MB h table retains more of it (the gather is the BW bottleneck).

__global__ __launch_bounds__(256) void att_fused_kernel(const short* __restrict__ h,
                                                        const float* __restrict__ alS,
                                                        const float* __restrict__ alD,
                                                        const unsigned* __restrict__ gmaxU,
                                                        const int* __restrict__ row_ptr,
                                                        const int* __restrict__ srcs,
                                                        const float* __restrict__ bias,
                                                        short* __restrict__ out, int n) {
    int node = blockIdx.x * 4 + (threadIdx.x >> 6);
    if (node >= n) return;
    int lane = threadIdx.x & 63;
    int head = lane >> 3, sub = lane & 7;
    int lo = row_ptr[node], hi = row_ptr[node + 1];
    float ald = alD[node * HEADS + head];
    float gm = unfkey(gmaxU[head]) + ald;
    float m = fmaxf(gm, NEG_SLOPE * gm);
    int vbase = (lane & 56) << 2;
    int choff = lane * 4;

    float denom = 0.f;
    float4 acc = make_float4(0.f, 0.f, 0.f, 0.f);

    int i = lo;
    for (; i + 8 <= hi; i += 8) {
        int sj = __builtin_nontemporal_load(&srcs[i + sub]);
        float x = alS[sj * HEADS + head] + ald;
        x = fmaxf(x, NEG_SLOPE * x);
        float wgt = __expf(x - m);
        denom += wgt;
        int wb = __builtin_bit_cast(int, wgt);
#pragma unroll
        for (int jj = 0; jj < 8; jj++) {
            float wj = __builtin_bit_cast(float,
                        __builtin_amdgcn_ds_bpermute(vbase + jj * 4, wb));
            int s = __builtin_amdgcn_readlane(sj, jj);
            uint2 u = *(const uint2*)&h[(size_t)s * HID + choff];
            acc.x += wj * bflo(u.x);
            acc.y += wj * bfhi(u.x);
            acc.z += wj * bflo(u.y);
            acc.w += wj * bfhi(u.y);
        }
    }
    if (i < hi) {
        int rem = hi - i;
        int sj = __builtin_nontemporal_load(&srcs[i + (sub < rem ? sub : 0)]);
        float x = alS[sj * HEADS + head] + ald;
        x = fmaxf(x, NEG_SLOPE * x);
        float we = __expf(x - m);
        float wgt = (sub < rem) ? we : 0.f;
        denom += wgt;
        int wb = __builtin_bit_cast(int, wgt);
        for (int jj = 0; jj < rem; jj++) {
            float wj = __builtin_bit_cast(float,
                        __builtin_amdgcn_ds_bpermute(vbase + jj * 4, wb));
            int s = __builtin_amdgcn_readlane(sj, jj);
            uint2 u = *(const uint2*)&h[(size_t)s * HID + choff];
            acc.x += wj * bflo(u.x);
            acc.y += wj * bfhi(u.x);
            acc.z += wj * bflo(u.y);
            acc.w += wj * bfhi(u.y);
        }
    }
    denom += __shfl_xor(denom, 1);
    denom += __shfl_xor(denom, 2);
    denom += __shfl_xor(denom, 4);

    float inv = 1.0f / (denom + 1e-16f);
    float4 b4 = *(const float4*)&bias[choff];
    union { uint2v u; __hip_bfloat162 b[2]; } p;
    p.b[0] = __float22bfloat162_rn(make_float2(acc.x * inv + b4.x, acc.y * inv + b4.y));
    p.b[1] = __float22bfloat162_rn(make_float2(acc.z * inv + b4.z, acc.w * inv + b4.w));
    __builtin_nontemporal_store(p.u, (uint2v*)&out[(size_t)node * HID + choff]);
}

// ---------------- parallel mean pool (bf16 input) ----------------

#define POOL_CHUNK 64

__global__ __launch_bounds__(256) void pool_accum_kernel(const short* __restrict__ h,
                                                         const int* __restrict__ batch,
                                                         float* __restrict__ pooled,
                                                         int* __restrict__ cnt, int n) {
    int c0 = blockIdx.x * POOL_CHUNK;
    int c1 = c0 + POOL_CHUNK; if (c1 > n) c1 = n;
    int t = threadIdx.x;
    int g_cur = batch[c0];
    float acc = 0.f;
    int run = 0;
    for (int i = c0; i < c1; i++) {
        int g = batch[i];
        if (g != g_cur) {
            atomicAdd(&pooled[g_cur * HID + t], acc);
            if (t == 0) atomicAdd(&cnt[g_cur], run);
            acc = 0.f; run = 0; g_cur = g;
        }
        acc += bf2f(h[(size_t)i * HID + t]);
        run++;
    }
    atomicAdd(&pooled[g_cur * HID + t], acc);
    if (t == 0) atomicAdd(&cnt[g_cur], run);
}

// ---------------- final linear (with mean divide) ----------------

__global__ void final_kernel(const float* __restrict__ pooled, const int* __restrict__ cnt,
                             const float* __restrict__ W, const float* __restrict__ b,
                             float* __restrict__ out) {
    int idx = blockIdx.x * blockDim.x + threadIdx.x;
    if (idx >= NGRAPH * 10) return;
    int g = idx / 10, o = idx % 10;
    int c = cnt[g];
    float inv = 1.0f / (float)(c > 0 ? c : 1);
    float acc = b[o];
    for (int k = 0; k < HID; k++) acc += pooled[g * HID + k] * inv * W[k * 10 + o];
    out[idx] = acc;
}

extern "C" void kernel_launch(void* const* d_in, const int* in_sizes, int n_in,
                              void* d_out, int out_size, void* d_ws, size_t ws_size,
                              hipStream_t stream) {
    const float* x      = (const float*)d_in[0];
    const int*   ei     = (const int*)d_in[1];
    const int*   batch  = (const int*)d_in[2];
    const float* W0     = (const float*)d_in[3];
    const float* a_src0 = (const float*)d_in[4];
    const float* a_dst0 = (const float*)d_in[5];
    const float* b0     = (const float*)d_in[6];
    const float* Wh     = (const float*)d_in[7];   // [2,256,256]
    const float* a_srch = (const float*)d_in[8];   // [2,8,32]
    const float* a_dsth = (const float*)d_in[9];
    const float* bh     = (const float*)d_in[10];  // [2,256]
    const float* W_lin  = (const float*)d_in[11];
    const float* b_lin  = (const float*)d_in[12];
    float* out = (float*)d_out;

    // workspace carve-up (pooled..counts contiguous for single memset)
    // Wt sizes: 17 tiles x KC x 64 x 8 shorts; layer0 KC=4 -> 34816, layers1/2 KC=8 -> 69632
    short* hA     = (short*)d_ws;                    // 50000*256 bf16 (GEMM out)
    short* hB     = hA + (size_t)NN * HID;           // 50000*256 bf16 (att out)
    short* Wt0    = hB + (size_t)NN * HID;           // 34816 (17-tile swizzled)
    short* Wt1    = Wt0 + 17 * 4 * 64 * 8;           // 69632
    short* Wt2    = Wt1 + 17 * 8 * 64 * 8;           // 69632
    float* alS    = (float*)(Wt2 + 17 * 8 * 64 * 8);
    float* alD    = alS + (size_t)NN * HEADS;
    float* pooled = alD + (size_t)NN * HEADS;        // 128*256
    int* cnt      = (int*)(pooled + NGRAPH * HID);   // 128
    unsigned* gmaxA = (unsigned*)(cnt + NGRAPH);     // 24 (3 layers x 8 heads)
    int* counts   = (int*)(gmaxA + 24);              // 50000
    int* row_ptr  = counts + NN;                     // 50001
    int* cursor   = row_ptr + NN + 1;                // 50000
    int* srcs     = cursor + NN;                     // 850000
    int* partial  = srcs + (NE + NN);                // 64

    const int NEP = NE + NN;
    const int NB_SCAN = (NN + 1023) / 1024;          // 49 <= 64
    const int NB_CNT = (NE + 255) / 256;             // 3125

    // single zero-init: pooled + cnt + gmaxA + counts
    hipMemsetAsync(pooled, 0, (NGRAPH * HID + NGRAPH + 24 + NN) * sizeof(float), stream);

    // fused W-swizzle (+wa cols) + edge-count
    prep_kernel<<<816 + NB_CNT, 256, 0, stream>>>(W0, Wh, a_src0, a_dst0, a_srch, a_dsth,
                                                  Wt0, Wt1, Wt2, ei + NE, counts, NE);
    scan_part_kernel<<<NB_SCAN, 1024, 0, stream>>>(counts, partial, NN);
    scan_final_kernel<<<NB_SCAN, 1024, 0, stream>>>(counts, partial, row_ptr, cursor, NN);
    scatter_kernel<<<(NEP + 255) / 256, 256, 0, stream>>>(ei, cursor, srcs, NE, NN);

    const int gemm_grid = (NN + 127) / 128;          // 391 <= 512 resident: no tail
    const int agg_grid = (NN + 3) / 4;

    for (int l = 0; l < 3; l++) {
        const float* bb = (l == 0) ? b0 : bh + (size_t)(l - 1) * HID;
        unsigned* gm = gmaxA + l * 8;

        if (l == 0)
            gemm_mfma_kernel<128, true><<<gemm_grid, 256, 0, stream>>>(
                x, Wt0, hA, alS, alD, gm, NN);
        else
            gemm_mfma_kernel<256, false><<<gemm_grid, 256, 0, stream>>>(
                hB, (l == 1) ? Wt1 : Wt2, hA, alS, alD, gm, NN);
        att_fused_kernel<<<agg_grid, 256, 0, stream>>>(hA, alS, alD, gm, row_ptr, srcs, bb, hB, NN);
    }

    // pool + final linear
    pool_accum_kernel<<<(NN + POOL_CHUNK - 1) / POOL_CHUNK, 256, 0, stream>>>(hB, batch, pooled, cnt, NN);
    final_kernel<<<(NGRAPH * 10 + 255) / 256, 256, 0, stream>>>(pooled, cnt, W_lin, b_lin, out);
}

// Round 8
// 490.898 us; speedup vs baseline: 1.9302x; 1.0386x over previous
//
#include <hip/hip_runtime.h>
#include <hip/hip_bf16.h>
#include <math.h>

#define NN 50000
#define NE 800000
#define NGRAPH 128
#define HEADS 8
#define CH 32
#define HID 256
#define NEG_SLOPE 0.2f

typedef __attribute__((ext_vector_type(8))) short short8;
typedef __attribute__((ext_vector_type(4))) short short4v;
typedef __attribute__((ext_vector_type(4))) float v4f;

__device__ inline float bflo(unsigned u) { return __builtin_bit_cast(float, u << 16); }
__device__ inline float bfhi(unsigned u) { return __builtin_bit_cast(float, u & 0xFFFF0000u); }
__device__ inline float bf2f(short s) {
    return __builtin_bit_cast(float, ((unsigned)(unsigned short)s) << 16);
}
__device__ inline short f2bf(float f) {
    __hip_bfloat16 b = __float2bfloat16(f);
    return __builtin_bit_cast(short, b);
}
// monotonic float<->uint order-preserving map (for atomicMax on floats)
__device__ inline unsigned fkey(float f) {
    unsigned u = __builtin_bit_cast(unsigned, f);
    return (u & 0x80000000u) ? ~u : (u | 0x80000000u);
}
__device__ inline float unfkey(unsigned u) {
    unsigned v = (u & 0x80000000u) ? (u & 0x7FFFFFFFu) : ~u;
    return __builtin_bit_cast(float, v);
}

// ---------------- fused prep ----------------
// blocks [0, 816): W swizzle-convert; per layer 272 cols: 0..255 = W cols,
//   cols 256..271 = wa[k][j] = sum_c W[k][head*32+c] * a[c]  (j<8: a_src head j; j>=8: a_dst head j-8)
// remaining blocks: edge count. counts[] pre-zeroed; self-loop = +1 in scans.

__global__ void prep_kernel(const float* __restrict__ W0, const float* __restrict__ Wh,
                            const float* __restrict__ as0, const float* __restrict__ ad0,
                            const float* __restrict__ ash, const float* __restrict__ adh,
                            short* __restrict__ Wt0, short* __restrict__ Wt1,
                            short* __restrict__ Wt2,
                            const int* __restrict__ dst, int* __restrict__ counts, int e) {
    int b = blockIdx.x;
    if (b < 816) {
        int which = b / 272;
        int n = b % 272;
        const float* W = (which == 0) ? W0 : (which == 1) ? Wh : Wh + 256 * 256;
        short* Wt = (which == 0) ? Wt0 : (which == 1) ? Wt1 : Wt2;
        const float* as = (which == 0) ? as0 : ash + (which - 1) * HEADS * CH;
        const float* ad = (which == 0) ? ad0 : adh + (which - 1) * HEADS * CH;
        int K = (which == 0) ? 128 : 256;
        int tile16 = n >> 4, l16 = n & 15;
        int KC = K >> 5;
        for (int k = threadIdx.x; k < K; k += blockDim.x) {
            float val;
            if (n < 256) {
                val = W[(size_t)k * 256 + n];
            } else {
                int j = n - 256;
                int head = j & 7;
                const float* a = (j < 8) ? (as + head * CH) : (ad + head * CH);
                float s = 0.f;
#pragma unroll
                for (int c = 0; c < CH; c++) s += W[(size_t)k * 256 + head * CH + c] * a[c];
                val = s;
            }
            int kc = k >> 5, quad = (k & 31) >> 3, j8 = k & 7;
            int lane = quad * 16 + l16;
            Wt[(size_t)(((tile16 * KC + kc) * 64 + lane)) * 8 + j8] = f2bf(val);
        }
    } else {
        int i = (b - 816) * 256 + threadIdx.x;
        if (i < e) atomicAdd(&counts[dst[i]], 1);
    }
}

__device__ inline int wave_incl_scan(int v, int lane) {
#pragma unroll
    for (int off = 1; off < 64; off <<= 1) {
        int u = __shfl_up(v, off);
        if (lane >= off) v += u;
    }
    return v;
}

__global__ __launch_bounds__(1024) void scan_part_kernel(const int* __restrict__ counts,
                                                         int* partial, int n) {
    int i = blockIdx.x * 1024 + threadIdx.x;
    int v = (i < n) ? counts[i] + 1 : 0;   // +1 self-loop
    int lane = threadIdx.x & 63, w = threadIdx.x >> 6;
    __shared__ int ws[16];
    int sv = wave_incl_scan(v, lane);
    if (lane == 63) ws[w] = sv;
    __syncthreads();
    if (threadIdx.x == 0) {
        int tot = 0;
#pragma unroll
        for (int j = 0; j < 16; j++) tot += ws[j];
        partial[blockIdx.x] = tot;
    }
}

// final scan; block-offset computed inline from partials (nb <= 64)
__global__ __launch_bounds__(1024) void scan_final_kernel(const int* __restrict__ counts,
                                                          const int* __restrict__ partial,
                                                          int* row_ptr, int* cursor, int n) {
    __shared__ int ws[17];
    __shared__ int s_off;
    int i = blockIdx.x * 1024 + threadIdx.x;
    int v = (i < n) ? counts[i] + 1 : 0;   // +1 self-loop
    int lane = threadIdx.x & 63, w = threadIdx.x >> 6;
    if (threadIdx.x < 64) {
        int pv = ((int)threadIdx.x < (int)blockIdx.x) ? partial[threadIdx.x] : 0;
#pragma unroll
        for (int off = 1; off < 64; off <<= 1) pv += __shfl_xor(pv, off);
        if (threadIdx.x == 0) s_off = pv;
    }
    int sv = wave_incl_scan(v, lane);
    if (lane == 63) ws[w] = sv;
    __syncthreads();
    if (w == 0) {
        int t = (lane < 16) ? ws[lane] : 0;
        int ts = wave_incl_scan(t, lane);
        if (lane < 16) ws[lane] = ts;
    }
    __syncthreads();
    int waveBase = (w > 0) ? ws[w - 1] : 0;
    int off = s_off;
    int incl = waveBase + sv;
    if (i < n) {
        int ex = off + incl - v;
        row_ptr[i] = ex;
        cursor[i] = ex;
        if (i == n - 1) row_ptr[n] = off + incl;
    }
}

__global__ void scatter_kernel(const int* __restrict__ ei, int* cursor, int* srcs, int ne, int nn) {
    int i = blockIdx.x * blockDim.x + threadIdx.x;
    if (i < ne) {
        int s = ei[i];
        int d = ei[ne + i];
        int pos = atomicAdd(&cursor[d], 1);
        srcs[pos] = s;
    } else if (i < ne + nn) {
        int v = i - ne;
        int pos = atomicAdd(&cursor[v], 1);
        srcs[pos] = v;
    }
}

// ---------------- MFMA GEMM + algebraic alpha (17th B-tile) ----------------
// H[M,256](bf16) = A[M,K] @ W(swizzled, 17 tiles); tile 16 = wa -> alS/alD in f32 acc.
// block = 128 rows x 256 cols, 4 waves; wave = 64 rows x 128 cols (4x8 mfma tiles).
// Waves with wn==0 additionally compute the wa tile for their 64 rows (+4 MFMA/kc).

#define EP_STRIDE 144

template <int K, bool AF32>
__global__ __launch_bounds__(256, 2) void gemm_mfma_kernel(const void* __restrict__ Ap,
                                                           const short* __restrict__ Wt,
                                                           short* __restrict__ H,
                                                           float* __restrict__ alS,
                                                           float* __restrict__ alD,
                                                           unsigned* __restrict__ gmaxU,
                                                           int M) {
    constexpr int KC = K >> 5;
    constexpr int ASTRIDE = K + 8;
    union LdsU {
        short a[128][ASTRIDE];
        short ep[4][64][EP_STRIDE];
    };
    __shared__ LdsU lds;
    __shared__ unsigned sm[HEADS];

    int t = threadIdx.x;
    int w = t >> 6;
    int lane = t & 63;
    int quad = lane >> 4, l16 = lane & 15;
    int wm = w & 1, wn = w >> 1;
    int m0 = blockIdx.x * 128;
    int m_base = m0 + wm * 64;
    int n_base = wn * 128;

    if (t < HEADS) sm[t] = 0u;

    // ---- stage A[128][K] into LDS, fully coalesced global reads ----
    if constexpr (AF32) {
        constexpr int C4 = K / 4;
        const float* A = (const float*)Ap;
        for (int s = t; s < 128 * C4; s += 256) {
            int row = s / C4;
            int c4 = s % C4;
            int gr = m0 + row; if (gr >= M) gr = M - 1;
            float4 v = *(const float4*)&A[(size_t)gr * K + c4 * 4];
            union { short4v s4; __hip_bfloat162 b[2]; } p;
            p.b[0] = __float22bfloat162_rn(make_float2(v.x, v.y));
            p.b[1] = __float22bfloat162_rn(make_float2(v.z, v.w));
            *(short4v*)&lds.a[row][c4 * 4] = p.s4;
        }
    } else {
        constexpr int C8 = K / 8;
        const short* A = (const short*)Ap;
        for (int s = t; s < 128 * C8; s += 256) {
            int row = s / C8;
            int c8 = s % C8;
            int gr = m0 + row; if (gr >= M) gr = M - 1;
            *(short8*)&lds.a[row][c8 * 8] = *(const short8*)&A[(size_t)gr * K + c8 * 8];
        }
    }
    __syncthreads();

    v4f acc[4][8] = {};
    v4f acce[4] = {};   // wa tile accumulators (wn==0 waves only; cols: l16<8 -> alS, else alD)
    // swizzled B base for this wave: tiles wn*8 .. wn*8+7
    const short* bw = Wt + ((size_t)(wn * 8) * KC * 64 + lane) * 8;
    const short* bwe = Wt + ((size_t)(16) * KC * 64 + lane) * 8;   // wa tile

#pragma unroll
    for (int kc = 0; kc < KC; kc++) {
        short8 b_frag[8];
#pragma unroll
        for (int nj = 0; nj < 8; nj++)
            b_frag[nj] = *(const short8*)(bw + (size_t)(nj * KC + kc) * 64 * 8);
        short8 a_frag[4];
#pragma unroll
        for (int mi = 0; mi < 4; mi++)
            a_frag[mi] = *(const short8*)&lds.a[wm * 64 + mi * 16 + l16][kc * 32 + quad * 8];
#pragma unroll
        for (int mi = 0; mi < 4; mi++)
#pragma unroll
            for (int nj = 0; nj < 8; nj++)
                acc[mi][nj] = __builtin_amdgcn_mfma_f32_16x16x32_bf16(a_frag[mi], b_frag[nj],
                                                                      acc[mi][nj], 0, 0, 0);
        if (wn == 0) {
            short8 be = *(const short8*)(bwe + (size_t)kc * 64 * 8);
#pragma unroll
            for (int mi = 0; mi < 4; mi++)
                acce[mi] = __builtin_amdgcn_mfma_f32_16x16x32_bf16(a_frag[mi], be,
                                                                   acce[mi], 0, 0, 0);
        }
    }
    __syncthreads();   // all lds.a reads complete before ep overwrite

    // ---- alS/alD write + per-head max (wn==0 waves; rows m_base..m_base+63) ----
    if (wn == 0) {
        float hmax = -1e30f;   // head = l16 (only meaningful for l16 < 8)
#pragma unroll
        for (int mi = 0; mi < 4; mi++)
#pragma unroll
            for (int r = 0; r < 4; r++) {
                int row = m_base + mi * 16 + quad * 4 + r;
                float v = acce[mi][r];
                if (row < M) {
                    if (l16 < 8) {
                        alS[row * HEADS + l16] = v;
                        hmax = fmaxf(hmax, v);
                    } else {
                        alD[row * HEADS + (l16 - 8)] = v;
                    }
                }
            }
        hmax = fmaxf(hmax, __shfl_xor(hmax, 16));
        hmax = fmaxf(hmax, __shfl_xor(hmax, 32));
        if (lane < 8) atomicMax(&sm[lane], fkey(hmax));
    }

#pragma unroll
    for (int mi = 0; mi < 4; mi++)
#pragma unroll
        for (int r = 0; r < 4; r++) {
            int rl = mi * 16 + quad * 4 + r;
#pragma unroll
            for (int nj = 0; nj < 8; nj++)
                lds.ep[w][rl][nj * 16 + l16] = f2bf(acc[mi][nj][r]);
        }
    __syncthreads();

    int rq = lane >> 4;
#pragma unroll
    for (int it = 0; it < 16; it++) {
        int rl = it * 4 + rq;
        int row = m_base + rl;
        if (row < M) {
            short8 v = *(const short8*)&lds.ep[w][rl][l16 * 8];
            *(short8*)&H[(size_t)row * HID + n_base + l16 * 8] = v;
        }
    }
    if (t < HEADS) atomicMax(&gmaxU[t], sm[t]);
}

// ---------------- fused attention: fixed-shift softmax, deep-MLP gather ----------------
// one wave per node; lane = head*8+sub owns channels [lane*4, lane*4+4).
// Main loop: 16 edges/iter. All 16 source indices extracted via readlane, all 16
// row-gather loads issued back-to-back (16x global_load_dwordx2 in flight), THEN
// weight broadcasts (bpermute) + fmacs. 2x the loads-in-flight of the 8-edge loop
// -> attacks the observed latency limit (3.6 TB/s @ 31% VALU, occupancy 70%).

__global__ __launch_bounds__(256) void att_fused_kernel(const short* __restrict__ h,
                                                        const float* __restrict__ alS,
                                                        const float* __restrict__ alD,
                                                        const unsigned* __restrict__ gmaxU,
                                                        const int* __restrict__ row_ptr,
                                                        const int* __restrict__ srcs,
                                                        const float* __restrict__ bias,
                                                        short* __restrict__ out, int n) {
    int node = blockIdx.x * 4 + (threadIdx.x >> 6);
    if (node >= n) return;
    int lane = threadIdx.x & 63;
    int head = lane >> 3, sub = lane & 7;
    int lo = row_ptr[node], hi = row_ptr[node + 1];
    float ald = alD[node * HEADS + head];
    float gm = unfkey(gmaxU[head]) + ald;
    float m = fmaxf(gm, NEG_SLOPE * gm);
    int vbase = (lane & 56) << 2;
    int choff = lane * 4;

    float denom = 0.f;
    float4 acc = make_float4(0.f, 0.f, 0.f, 0.f);

    int i = lo;
    for (; i + 16 <= hi; i += 16) {
        int sj0 = srcs[i + sub];
        int sj1 = srcs[i + 8 + sub];
        // issue all 16 gathers first (max loads in flight)
        uint2 u0[8], u1[8];
#pragma unroll
        for (int jj = 0; jj < 8; jj++) {
            int s0 = __builtin_amdgcn_readlane(sj0, jj);
            u0[jj] = *(const uint2*)&h[(size_t)s0 * HID + choff];
        }
#pragma unroll
        for (int jj = 0; jj < 8; jj++) {
            int s1 = __builtin_amdgcn_readlane(sj1, jj);
            u1[jj] = *(const uint2*)&h[(size_t)s1 * HID + choff];
        }
        float x0 = alS[sj0 * HEADS + head] + ald;
        float x1 = alS[sj1 * HEADS + head] + ald;
        x0 = fmaxf(x0, NEG_SLOPE * x0);
        x1 = fmaxf(x1, NEG_SLOPE * x1);
        float w0 = __expf(x0 - m);
        float w1 = __expf(x1 - m);
        denom += w0 + w1;
        int wb0 = __builtin_bit_cast(int, w0);
        int wb1 = __builtin_bit_cast(int, w1);
#pragma unroll
        for (int jj = 0; jj < 8; jj++) {
            float wj0 = __builtin_bit_cast(float,
                         __builtin_amdgcn_ds_bpermute(vbase + jj * 4, wb0));
            acc.x += wj0 * bflo(u0[jj].x);
            acc.y += wj0 * bfhi(u0[jj].x);
            acc.z += wj0 * bflo(u0[jj].y);
            acc.w += wj0 * bfhi(u0[jj].y);
            float wj1 = __builtin_bit_cast(float,
                         __builtin_amdgcn_ds_bpermute(vbase + jj * 4, wb1));
            acc.x += wj1 * bflo(u1[jj].x);
            acc.y += wj1 * bfhi(u1[jj].x);
            acc.z += wj1 * bflo(u1[jj].y);
            acc.w += wj1 * bfhi(u1[jj].y);
        }
    }
    for (; i + 8 <= hi; i += 8) {
        int sj = srcs[i + sub];
        float x = alS[sj * HEADS + head] + ald;
        x = fmaxf(x, NEG_SLOPE * x);
        float wgt = __expf(x - m);
        denom += wgt;
        int wb = __builtin_bit_cast(int, wgt);
#pragma unroll
        for (int jj = 0; jj < 8; jj++) {
            float wj = __builtin_bit_cast(float,
                        __builtin_amdgcn_ds_bpermute(vbase + jj * 4, wb));
            int s = __builtin_amdgcn_readlane(sj, jj);
            uint2 u = *(const uint2*)&h[(size_t)s * HID + choff];
            acc.x += wj * bflo(u.x);
            acc.y += wj * bfhi(u.x);
            acc.z += wj * bflo(u.y);
            acc.w += wj * bfhi(u.y);
        }
    }
    if (i < hi) {
        int rem = hi - i;
        int sj = srcs[i + (sub < rem ? sub : 0)];
        float x = alS[sj * HEADS + head] + ald;
        x = fmaxf(x, NEG_SLOPE * x);
        float we = __expf(x - m);
        float wgt = (sub < rem) ? we : 0.f;
        denom += wgt;
        int wb = __builtin_bit_cast(int, wgt);
        for (int jj = 0; jj < rem; jj++) {
            float wj = __builtin_bit_cast(float,
                        __builtin_amdgcn_ds_bpermute(vbase + jj * 4, wb));
            int s = __builtin_amdgcn_readlane(sj, jj);
            uint2 u = *(const uint2*)&h[(size_t)s * HID + choff];
            acc.x += wj * bflo(u.x);
            acc.y += wj * bfhi(u.x);
            acc.z += wj * bflo(u.y);
            acc.w += wj * bfhi(u.y);
        }
    }
    denom += __shfl_xor(denom, 1);
    denom += __shfl_xor(denom, 2);
    denom += __shfl_xor(denom, 4);

    float inv = 1.0f / (denom + 1e-16f);
    float4 b4 = *(const float4*)&bias[choff];
    union { uint2 u; __hip_bfloat162 b[2]; } p;
    p.b[0] = __float22bfloat162_rn(make_float2(acc.x * inv + b4.x, acc.y * inv + b4.y));
    p.b[1] = __float22bfloat162_rn(make_float2(acc.z * inv + b4.z, acc.w * inv + b4.w));
    *(uint2*)&out[(size_t)node * HID + choff] = p.u;
}

// ---------------- parallel mean pool (bf16 input) ----------------

#define POOL_CHUNK 64

__global__ __launch_bounds__(256) void pool_accum_kernel(const short* __restrict__ h,
                                                         const int* __restrict__ batch,
                                                         float* __restrict__ pooled,
                                                         int* __restrict__ cnt, int n) {
    int c0 = blockIdx.x * POOL_CHUNK;
    int c1 = c0 + POOL_CHUNK; if (c1 > n) c1 = n;
    int t = threadIdx.x;
    int g_cur = batch[c0];
    float acc = 0.f;
    int run = 0;
    for (int i = c0; i < c1; i++) {
        int g = batch[i];
        if (g != g_cur) {
            atomicAdd(&pooled[g_cur * HID + t], acc);
            if (t == 0) atomicAdd(&cnt[g_cur], run);
            acc = 0.f; run = 0; g_cur = g;
        }
        acc += bf2f(h[(size_t)i * HID + t]);
        run++;
    }
    atomicAdd(&pooled[g_cur * HID + t], acc);
    if (t == 0) atomicAdd(&cnt[g_cur], run);
}

// ---------------- final linear (with mean divide) ----------------

__global__ void final_kernel(const float* __restrict__ pooled, const int* __restrict__ cnt,
                             const float* __restrict__ W, const float* __restrict__ b,
                             float* __restrict__ out) {
    int idx = blockIdx.x * blockDim.x + threadIdx.x;
    if (idx >= NGRAPH * 10) return;
    int g = idx / 10, o = idx % 10;
    int c = cnt[g];
    float inv = 1.0f / (float)(c > 0 ? c : 1);
    float acc = b[o];
    for (int k = 0; k < HID; k++) acc += pooled[g * HID + k] * inv * W[k * 10 + o];
    out[idx] = acc;
}

extern "C" void kernel_launch(void* const* d_in, const int* in_sizes, int n_in,
                              void* d_out, int out_size, void* d_ws, size_t ws_size,
                              hipStream_t stream) {
    const float* x      = (const float*)d_in[0];
    const int*   ei     = (const int*)d_in[1];
    const int*   batch  = (const int*)d_in[2];
    const float* W0     = (const float*)d_in[3];
    const float* a_src0 = (const float*)d_in[4];
    const float* a_dst0 = (const float*)d_in[5];
    const float* b0     = (const float*)d_in[6];
    const float* Wh     = (const float*)d_in[7];   // [2,256,256]
    const float* a_srch = (const float*)d_in[8];   // [2,8,32]
    const float* a_dsth = (const float*)d_in[9];
    const float* bh     = (const float*)d_in[10];  // [2,256]
    const float* W_lin  = (const float*)d_in[11];
    const float* b_lin  = (const float*)d_in[12];
    float* out = (float*)d_out;

    // workspace carve-up (pooled..counts contiguous for single memset)
    // Wt sizes: 17 tiles x KC x 64 x 8 shorts; layer0 KC=4 -> 34816, layers1/2 KC=8 -> 69632
    short* hA     = (short*)d_ws;                    // 50000*256 bf16 (GEMM out)
    short* hB     = hA + (size_t)NN * HID;           // 50000*256 bf16 (att out)
    short* Wt0    = hB + (size_t)NN * HID;           // 34816 (17-tile swizzled)
    short* Wt1    = Wt0 + 17 * 4 * 64 * 8;           // 69632
    short* Wt2    = Wt1 + 17 * 8 * 64 * 8;           // 69632
    float* alS    = (float*)(Wt2 + 17 * 8 * 64 * 8);
    float* alD    = alS + (size_t)NN * HEADS;
    float* pooled = alD + (size_t)NN * HEADS;        // 128*256
    int* cnt      = (int*)(pooled + NGRAPH * HID);   // 128
    unsigned* gmaxA = (unsigned*)(cnt + NGRAPH);     // 24 (3 layers x 8 heads)
    int* counts   = (int*)(gmaxA + 24);              // 50000
    int* row_ptr  = counts + NN;                     // 50001
    int* cursor   = row_ptr + NN + 1;                // 50000
    int* srcs     = cursor + NN;                     // 850000
    int* partial  = srcs + (NE + NN);                // 64

    const int NEP = NE + NN;
    const int NB_SCAN = (NN + 1023) / 1024;          // 49 <= 64
    const int NB_CNT = (NE + 255) / 256;             // 3125

    // single zero-init: pooled + cnt + gmaxA + counts
    hipMemsetAsync(pooled, 0, (NGRAPH * HID + NGRAPH + 24 + NN) * sizeof(float), stream);

    // fused W-swizzle (+wa cols) + edge-count
    prep_kernel<<<816 + NB_CNT, 256, 0, stream>>>(W0, Wh, a_src0, a_dst0, a_srch, a_dsth,
                                                  Wt0, Wt1, Wt2, ei + NE, counts, NE);
    scan_part_kernel<<<NB_SCAN, 1024, 0, stream>>>(counts, partial, NN);
    scan_final_kernel<<<NB_SCAN, 1024, 0, stream>>>(counts, partial, row_ptr, cursor, NN);
    scatter_kernel<<<(NEP + 255) / 256, 256, 0, stream>>>(ei, cursor, srcs, NE, NN);

    const int gemm_grid = (NN + 127) / 128;          // 391 <= 512 resident: no tail
    const int agg_grid = (NN + 3) / 4;

    for (int l = 0; l < 3; l++) {
        const float* bb = (l == 0) ? b0 : bh + (size_t)(l - 1) * HID;
        unsigned* gm = gmaxA + l * 8;

        if (l == 0)
            gemm_mfma_kernel<128, true><<<gemm_grid, 256, 0, stream>>>(
                x, Wt0, hA, alS, alD, gm, NN);
        else
            gemm_mfma_kernel<256, false><<<gemm_grid, 256, 0, stream>>>(
                hB, (l == 1) ? Wt1 : Wt2, hA, alS, alD, gm, NN);
        att_fused_kernel<<<agg_grid, 256, 0, stream>>>(hA, alS, alD, gm, row_ptr, srcs, bb, hB, NN);
    }

    // pool + final linear
    pool_accum_kernel<<<(NN + POOL_CHUNK - 1) / POOL_CHUNK, 256, 0, stream>>>(hB, batch, pooled, cnt, NN);
    final_kernel<<<(NGRAPH * 10 + 255) / 256, 256, 0, stream>>>(pooled, cnt, W_lin, b_lin, out);
}